// Round 3
// baseline (4939.318 us; speedup 1.0000x reference)
//
#include <hip/hip_runtime.h>

#define THREADS 256
#define NPB 32              // nodes per bucket
#define LOG_NPB 5
#define AGG_LD 260          // padded LDS leading dim (floats): bank = (4r + c) % 32

typedef __attribute__((ext_vector_type(8))) short short8;
typedef __attribute__((ext_vector_type(4))) float f32x4;

__device__ __forceinline__ unsigned short f2bf(float f) {
    unsigned u = __builtin_bit_cast(unsigned, f);
    return (unsigned short)((u + 0x7FFFu + ((u >> 16) & 1u)) >> 16);  // RNE
}
__device__ __forceinline__ float bf2f_lo(unsigned u) { return __builtin_bit_cast(float, u << 16); }
__device__ __forceinline__ float bf2f_hi(unsigned u) { return __builtin_bit_cast(float, u & 0xFFFF0000u); }

// ---------------- bucket hist / scan / place ----------------

__global__ void zero_kernel(int* __restrict__ p, int n) {
    int i = blockIdx.x * blockDim.x + threadIdx.x;
    if (i < n) p[i] = 0;
}

// LDS-aggregated bucket histogram (nb <= 4096)
__global__ void bhist_kernel(const int* __restrict__ row, int* __restrict__ bcnt,
                             int n_edges, int nb) {
    __shared__ int h[4096];
    for (int i = threadIdx.x; i < nb; i += THREADS) h[i] = 0;
    __syncthreads();
    int stride = gridDim.x * THREADS;
    for (int e = blockIdx.x * THREADS + threadIdx.x; e < n_edges; e += stride)
        atomicAdd(&h[row[e] >> LOG_NPB], 1);
    __syncthreads();
    for (int i = threadIdx.x; i < nb; i += THREADS)
        if (h[i]) atomicAdd(&bcnt[i], h[i]);
}

// fallback if nb > 4096 (not expected at this size)
__global__ void hist_global_kernel(const int* __restrict__ row, int* __restrict__ bcnt, int n) {
    int stride = gridDim.x * blockDim.x;
    for (int e = blockIdx.x * blockDim.x + threadIdx.x; e < n; e += stride)
        atomicAdd(&bcnt[row[e] >> LOG_NPB], 1);
}

// single-block chunked exclusive scan; offs[0..n], cur[i]=offs[i]
__global__ void bscan_kernel(const int* __restrict__ cnt, int* __restrict__ offs,
                             int* __restrict__ cur, int n) {
    __shared__ int buf[2][THREADS];
    __shared__ int running_s;
    int tid = threadIdx.x;
    if (tid == 0) running_s = 0;
    __syncthreads();
    for (int base = 0; base < n; base += THREADS) {
        int idx = base + tid;
        int v = (idx < n) ? cnt[idx] : 0;
        int incl = v;
        int cb = 0;
        buf[0][tid] = incl;
        __syncthreads();
        #pragma unroll
        for (int off = 1; off < THREADS; off <<= 1) {
            int t = incl;
            if (tid >= off) t += buf[cb][tid - off];
            cb ^= 1;
            buf[cb][tid] = t;
            incl = t;
            __syncthreads();
        }
        int base_run = running_s;
        if (idx < n) {
            int excl = base_run + incl - v;
            offs[idx] = excl;
            cur[idx] = excl;
        }
        int total = buf[cb][THREADS - 1];
        __syncthreads();
        if (tid == 0) running_s = base_run + total;
        __syncthreads();
    }
    if (tid == 0) offs[n] = running_s;
}

// XCD-partitioned bucket-granularity scatter.
// group g = blockIdx & 7 (default dispatch: round-robin over 8 XCDs) owns rows
// [g*N/8,(g+1)*N/8): its bucket counters + tmp windows stay in ONE XCD's L2.
__global__ void place2_kernel(const int* __restrict__ row, const int* __restrict__ col,
                              const float* __restrict__ val, int* __restrict__ bcur,
                              uint2* __restrict__ tmp, int n_edges, int n_nodes) {
    int g = blockIdx.x & 7;
    int inst = blockIdx.x >> 3;
    int ninst = gridDim.x >> 3;
    int lo = (int)(((long long)g * n_nodes) >> 3);
    int hi = (int)(((long long)(g + 1) * n_nodes) >> 3);
    int e0 = (int)(((long long)inst * n_edges) / ninst);
    int e1 = (int)(((long long)(inst + 1) * n_edges) / ninst);
    for (int e = e0 + threadIdx.x; e < e1; e += THREADS) {
        int r = row[e];
        if (r >= lo && r < hi) {
            int p = atomicAdd(&bcur[r >> LOG_NPB], 1);
            tmp[p] = make_uint2(((unsigned)(r & (NPB - 1)) << 27) | (unsigned)col[e],
                                (unsigned)__float_as_int(val[e]));
        }
    }
}

// ---------------- f32 -> bf16 convert (8 elems/thread) ----------------

__global__ void cvt_bf16_kernel(const float4* __restrict__ in, uint4* __restrict__ out, int n8) {
    int i = blockIdx.x * blockDim.x + threadIdx.x;
    if (i >= n8) return;
    float4 a = in[2 * i], b = in[2 * i + 1];
    uint4 o;
    o.x = (unsigned)f2bf(a.x) | ((unsigned)f2bf(a.y) << 16);
    o.y = (unsigned)f2bf(a.z) | ((unsigned)f2bf(a.w) << 16);
    o.z = (unsigned)f2bf(b.x) | ((unsigned)f2bf(b.y) << 16);
    o.w = (unsigned)f2bf(b.z) | ((unsigned)f2bf(b.w) << 16);
    out[i] = o;
}

// ---------------- fused bucket-SpMM (LDS f32 atomics) + MFMA GEMM ----------------
// Block -> one 32-node bucket. Phase 1: accumulate agg[32][256] in LDS from
// bf16 gathers. Phase 2: bf16(agg) @ Wb^T + bias -> out rows, via MFMA.
__launch_bounds__(THREADS)
__global__ void spmm_gemm_kernel(const unsigned* __restrict__ xb,   // bf16 pairs [N][128]
                                 const uint2* __restrict__ tmp,     // bucket-major edges
                                 const int* __restrict__ boffs,
                                 const unsigned short* __restrict__ Wb,  // [256][256] bf16
                                 const float* __restrict__ bias,
                                 float* __restrict__ out,
                                 int n_nodes, int nb) {
    __shared__ float agg[NPB * AGG_LD];
    int tid = threadIdx.x;
    // swizzle: group g = blockIdx&7 handles buckets [g*nb/8,(g+1)*nb/8) so the
    // spmm reader XCD matches the place2 writer XCD for this bucket's tmp data.
    int g = blockIdx.x & 7, inst = blockIdx.x >> 3;
    int bstart = (int)(((long long)g * nb) >> 3);
    int bend = (int)(((long long)(g + 1) * nb) >> 3);
    int bkt = bstart + inst;
    if (bkt >= bend) return;

    for (int i = tid; i < NPB * AGG_LD / 4; i += THREADS)
        reinterpret_cast<float4*>(agg)[i] = make_float4(0.f, 0.f, 0.f, 0.f);
    __syncthreads();

    int s = boffs[bkt], e = boffs[bkt + 1];
    int lane = tid & 63;
    int w = __builtin_amdgcn_readfirstlane(tid >> 6);
    #pragma unroll 2
    for (int i = s + w; i < e; i += 4) {
        uint2 p = tmp[i];                       // wave-uniform -> scalar load
        float v = __int_as_float((int)p.y);
        int c = (int)(p.x & 0x07FFFFFFu);
        int rl = (int)(p.x >> 27);
        unsigned x0 = xb[(size_t)c * 128 + lane];        // features 2l, 2l+1
        unsigned x1 = xb[(size_t)c * 128 + 64 + lane];   // features 128+2l, +1
        float* a = &agg[rl * AGG_LD + 2 * lane];
        atomicAdd(a + 0, v * bf2f_lo(x0));
        atomicAdd(a + 1, v * bf2f_hi(x0));
        atomicAdd(a + 128, v * bf2f_lo(x1));
        atomicAdd(a + 129, v * bf2f_hi(x1));
    }
    __syncthreads();

    // phase 2: wave w -> 16-row half (w&1), 128-col half (w>>1); 8 n-tiles
    int mhalf = w & 1;
    int ncol0 = (w >> 1) * 128;
    int lr = lane & 15, lg = lane >> 4;
    f32x4 acc[8];
    #pragma unroll
    for (int nt = 0; nt < 8; ++nt) acc[nt] = (f32x4){0.f, 0.f, 0.f, 0.f};

    for (int k0 = 0; k0 < 256; k0 += 32) {
        const float* ap = &agg[(mhalf * 16 + lr) * AGG_LD + k0 + 8 * lg];
        float4 a0 = *reinterpret_cast<const float4*>(ap);
        float4 a1 = *reinterpret_cast<const float4*>(ap + 4);
        short8 af;
        af[0] = (short)f2bf(a0.x); af[1] = (short)f2bf(a0.y);
        af[2] = (short)f2bf(a0.z); af[3] = (short)f2bf(a0.w);
        af[4] = (short)f2bf(a1.x); af[5] = (short)f2bf(a1.y);
        af[6] = (short)f2bf(a1.z); af[7] = (short)f2bf(a1.w);
        #pragma unroll
        for (int nt = 0; nt < 8; ++nt) {
            short8 bf_ = *reinterpret_cast<const short8*>(
                &Wb[(size_t)(ncol0 + nt * 16 + lr) * 256 + k0 + 8 * lg]);
            acc[nt] = __builtin_amdgcn_mfma_f32_16x16x32_bf16(af, bf_, acc[nt], 0, 0, 0);
        }
    }

    int row0 = bkt * NPB + mhalf * 16;
    #pragma unroll
    for (int nt = 0; nt < 8; ++nt) {
        int gc = ncol0 + nt * 16 + lr;
        float bv = bias[gc];
        #pragma unroll
        for (int q = 0; q < 4; ++q) {
            int gr = row0 + lg * 4 + q;
            if (gr < n_nodes) out[(size_t)gr * 256 + gc] = acc[nt][q] + bv;
        }
    }
}

// ---------------- launch ----------------

extern "C" void kernel_launch(void* const* d_in, const int* in_sizes, int n_in,
                              void* d_out, int out_size, void* d_ws, size_t ws_size,
                              hipStream_t stream) {
    const float* x     = (const float*)d_in[0];
    const int*   erow  = (const int*)d_in[1];
    const int*   ecol  = (const int*)d_in[2];
    const float* evalv = (const float*)d_in[3];
    const float* W     = (const float*)d_in[4];
    const float* bias  = (const float*)d_in[5];
    float* out = (float*)d_out;

    int n_nodes = in_sizes[0] / 256;
    int n_edges = in_sizes[1];
    int nb = (n_nodes + NPB - 1) / NPB;

    // workspace layout (int units): bcnt | boffs | bcur | Wb | tmp | xb  (~77 MB)
    int* bcnt = (int*)d_ws;
    int* boffs = bcnt + ((nb + 63) & ~63);
    int* bcur = boffs + ((nb + 1 + 63) & ~63);
    unsigned short* Wb = (unsigned short*)(bcur + ((nb + 63) & ~63));
    uint2* tmp = (uint2*)(Wb + 65536);
    unsigned* xb = (unsigned*)(tmp + n_edges);

    zero_kernel<<<(nb + THREADS - 1) / THREADS, THREADS, 0, stream>>>(bcnt, nb);
    if (nb <= 4096)
        bhist_kernel<<<64, THREADS, 0, stream>>>(erow, bcnt, n_edges, nb);
    else
        hist_global_kernel<<<1024, THREADS, 0, stream>>>(erow, bcnt, n_edges);
    bscan_kernel<<<1, THREADS, 0, stream>>>(bcnt, boffs, bcur, nb);
    place2_kernel<<<768, THREADS, 0, stream>>>(erow, ecol, evalv, bcur, tmp, n_edges, n_nodes);

    cvt_bf16_kernel<<<32, THREADS, 0, stream>>>((const float4*)W, (uint4*)Wb, 65536 / 8);
    int n8 = n_nodes * 32;  // n_nodes*256/8
    cvt_bf16_kernel<<<(n8 + THREADS - 1) / THREADS, THREADS, 0, stream>>>(
        (const float4*)x, (uint4*)xb, n8);

    int ninst_g = (nb + 7) / 8;
    spmm_gemm_kernel<<<8 * ninst_g, THREADS, 0, stream>>>(
        xb, tmp, boffs, Wb, bias, out, n_nodes, nb);
}

// Round 4
// 665.318 us; speedup vs baseline: 7.4240x; 7.4240x over previous
//
#include <hip/hip_runtime.h>

#define THREADS 256

typedef __attribute__((ext_vector_type(8))) short short8;
typedef __attribute__((ext_vector_type(4))) float f32x4;

__device__ __forceinline__ unsigned short f2bf(float f) {
    unsigned u = __builtin_bit_cast(unsigned, f);
    return (unsigned short)((u + 0x7FFFu + ((u >> 16) & 1u)) >> 16);  // RNE
}
__device__ __forceinline__ float bf2f_lo(unsigned u) { return __builtin_bit_cast(float, u << 16); }
__device__ __forceinline__ float bf2f_hi(unsigned u) { return __builtin_bit_cast(float, u & 0xFFFF0000u); }

// ---------------- CSR build (XCD-partitioned hist + place) ----------------

__global__ void zero_kernel(int* __restrict__ p, int n) {
    int i = blockIdx.x * blockDim.x + threadIdx.x;
    if (i < n) p[i] = 0;
}

// group g = blockIdx&7 (default dispatch round-robins blocks over the 8 XCDs)
// owns rows [g*N/8,(g+1)*N/8): cnt lines for those rows are only touched by
// one XCD -> no cross-XCD line migration. Each group re-reads the full row
// array (sequential, L3/HBM-friendly).
__global__ void hist_part_kernel(const int* __restrict__ row, int* __restrict__ cnt,
                                 int n_edges, int n_nodes) {
    int g = blockIdx.x & 7;
    int inst = blockIdx.x >> 3;
    int ninst = gridDim.x >> 3;
    int lo = (int)(((long long)g * n_nodes) >> 3);
    int hi = (int)(((long long)(g + 1) * n_nodes) >> 3);
    int e0 = (int)(((long long)inst * n_edges) / ninst);
    int e1 = (int)(((long long)(inst + 1) * n_edges) / ninst);
    for (int e = e0 + threadIdx.x; e < e1; e += THREADS) {
        int r = row[e];
        if (r >= lo && r < hi) atomicAdd(&cnt[r], 1);
    }
}

// scan1: per-block (1024 elems) exclusive scan into offs, block sums into bsum
__global__ void scan1_kernel(const int* __restrict__ cnt, int* __restrict__ offs,
                             int* __restrict__ bsum, int n) {
    int tid = threadIdx.x;
    int base = blockIdx.x * 1024 + tid * 4;
    int v0 = 0, v1 = 0, v2 = 0, v3 = 0;
    if (base + 3 < n) {
        int4 v = *reinterpret_cast<const int4*>(cnt + base);
        v0 = v.x; v1 = v.y; v2 = v.z; v3 = v.w;
    } else {
        if (base + 0 < n) v0 = cnt[base + 0];
        if (base + 1 < n) v1 = cnt[base + 1];
        if (base + 2 < n) v2 = cnt[base + 2];
    }
    int ts = v0 + v1 + v2 + v3;
    int lane = tid & 63;
    int incl = ts;
    #pragma unroll
    for (int off = 1; off < 64; off <<= 1) {
        int t = __shfl_up(incl, off, 64);
        if (lane >= off) incl += t;
    }
    __shared__ int wsum[4];
    int w = tid >> 6;
    if (lane == 63) wsum[w] = incl;
    __syncthreads();
    int wo = 0;
    for (int i = 0; i < w; ++i) wo += wsum[i];
    int excl = wo + incl - ts;
    if (base + 0 < n) offs[base + 0] = excl;
    if (base + 1 < n) offs[base + 1] = excl + v0;
    if (base + 2 < n) offs[base + 2] = excl + v0 + v1;
    if (base + 3 < n) offs[base + 3] = excl + v0 + v1 + v2;
    if (tid == THREADS - 1) bsum[blockIdx.x] = wo + incl;
}

// scan2: single block, exclusive scan of bsum[0..nb), total -> bsum[nb]
__global__ void scan2_kernel(int* __restrict__ bsum, int nb) {
    int tid = threadIdx.x;
    int base = tid * 4;
    int v0 = 0, v1 = 0, v2 = 0, v3 = 0;
    if (base + 0 < nb) v0 = bsum[base + 0];
    if (base + 1 < nb) v1 = bsum[base + 1];
    if (base + 2 < nb) v2 = bsum[base + 2];
    if (base + 3 < nb) v3 = bsum[base + 3];
    int ts = v0 + v1 + v2 + v3;
    int lane = tid & 63;
    int incl = ts;
    #pragma unroll
    for (int off = 1; off < 64; off <<= 1) {
        int t = __shfl_up(incl, off, 64);
        if (lane >= off) incl += t;
    }
    __shared__ int wsum[4];
    int w = tid >> 6;
    if (lane == 63) wsum[w] = incl;
    __syncthreads();
    int wo = 0;
    for (int i = 0; i < w; ++i) wo += wsum[i];
    int excl = wo + incl - ts;
    if (base + 0 < nb) bsum[base + 0] = excl;
    if (base + 1 < nb) bsum[base + 1] = excl + v0;
    if (base + 2 < nb) bsum[base + 2] = excl + v0 + v1;
    if (base + 3 < nb) bsum[base + 3] = excl + v0 + v1 + v2;
    if (tid == THREADS - 1) bsum[nb] = wo + incl;
}

// scan3: offs[i] += bsum[i>>10]; cur[i] = offs[i]; offs[n] = total
__global__ void scan3_kernel(int* __restrict__ offs, const int* __restrict__ bsum,
                             int* __restrict__ cur, int n) {
    int i = blockIdx.x * blockDim.x + threadIdx.x;
    if (i < n) {
        int v = offs[i] + bsum[i >> 10];
        offs[i] = v;
        cur[i] = v;
    }
    if (i == 0) offs[n] = bsum[(n + 1023) >> 10];
}

// XCD-partitioned fine-grained CSR scatter: group g only places edges whose
// row is in its range, so each CSR segment + cur counter line is written by
// exactly one XCD (kills the 8x write amplification seen in round 2).
__global__ void place_part_kernel(const int* __restrict__ row, const int* __restrict__ col,
                                  const float* __restrict__ val, int* __restrict__ cur,
                                  int2* __restrict__ pr, int n_edges, int n_nodes) {
    int g = blockIdx.x & 7;
    int inst = blockIdx.x >> 3;
    int ninst = gridDim.x >> 3;
    int lo = (int)(((long long)g * n_nodes) >> 3);
    int hi = (int)(((long long)(g + 1) * n_nodes) >> 3);
    int e0 = (int)(((long long)inst * n_edges) / ninst);
    int e1 = (int)(((long long)(inst + 1) * n_edges) / ninst);
    for (int e = e0 + threadIdx.x; e < e1; e += THREADS) {
        int r = row[e];
        if (r >= lo && r < hi) {
            int p = atomicAdd(&cur[r], 1);
            pr[p] = make_int2(col[e], __float_as_int(val[e]));
        }
    }
}

// ---------------- f32 -> bf16 convert (8 elems/thread) ----------------

__global__ void cvt_bf16_kernel(const float4* __restrict__ in, uint4* __restrict__ out, int n8) {
    int i = blockIdx.x * blockDim.x + threadIdx.x;
    if (i >= n8) return;
    float4 a = in[2 * i], b = in[2 * i + 1];
    uint4 o;
    o.x = (unsigned)f2bf(a.x) | ((unsigned)f2bf(a.y) << 16);
    o.y = (unsigned)f2bf(a.z) | ((unsigned)f2bf(a.w) << 16);
    o.z = (unsigned)f2bf(b.x) | ((unsigned)f2bf(b.y) << 16);
    o.w = (unsigned)f2bf(b.z) | ((unsigned)f2bf(b.w) << 16);
    out[i] = o;
}

// ---------------- SpMM: one wave64 per node, bf16 gathers, x8 unroll ----------------
// Lane owns features [4*lane .. 4*lane+3]; per edge the wave reads 64 x uint2
// (one 512B coalesced row); 8 independent gathers in flight per wave.
__global__ void spmm_bf16_kernel(const uint2* __restrict__ xb, const int* __restrict__ offs,
                                 const int2* __restrict__ pr, float4* __restrict__ out4,
                                 int nnodes) {
    int wid = (blockIdx.x * blockDim.x + threadIdx.x) >> 6;
    int lane = threadIdx.x & 63;
    if (wid >= nnodes) return;
    int s = offs[wid], e = offs[wid + 1];
    float a0 = 0.f, a1 = 0.f, a2 = 0.f, a3 = 0.f;
    int i = s;
    if (i < e && (i & 1)) {  // align to even for int4 pair loads
        int2 p = pr[i];
        uint2 xv = xb[(size_t)p.x * 64 + lane];
        float v = __int_as_float(p.y);
        a0 = fmaf(v, bf2f_lo(xv.x), a0);
        a1 = fmaf(v, bf2f_hi(xv.x), a1);
        a2 = fmaf(v, bf2f_lo(xv.y), a2);
        a3 = fmaf(v, bf2f_hi(xv.y), a3);
        ++i;
    }
    for (; i + 8 <= e; i += 8) {
        int4 pa = *reinterpret_cast<const int4*>(pr + i);
        int4 pb = *reinterpret_cast<const int4*>(pr + i + 2);
        int4 pc = *reinterpret_cast<const int4*>(pr + i + 4);
        int4 pd = *reinterpret_cast<const int4*>(pr + i + 6);
        uint2 x0 = xb[(size_t)pa.x * 64 + lane];
        uint2 x1 = xb[(size_t)pa.z * 64 + lane];
        uint2 x2 = xb[(size_t)pb.x * 64 + lane];
        uint2 x3 = xb[(size_t)pb.z * 64 + lane];
        uint2 x4_ = xb[(size_t)pc.x * 64 + lane];
        uint2 x5 = xb[(size_t)pc.z * 64 + lane];
        uint2 x6 = xb[(size_t)pd.x * 64 + lane];
        uint2 x7 = xb[(size_t)pd.z * 64 + lane];
        float v0 = __int_as_float(pa.y), v1 = __int_as_float(pa.w);
        float v2 = __int_as_float(pb.y), v3 = __int_as_float(pb.w);
        float v4 = __int_as_float(pc.y), v5 = __int_as_float(pc.w);
        float v6 = __int_as_float(pd.y), v7 = __int_as_float(pd.w);
        a0 = fmaf(v0, bf2f_lo(x0.x), a0); a1 = fmaf(v0, bf2f_hi(x0.x), a1);
        a2 = fmaf(v0, bf2f_lo(x0.y), a2); a3 = fmaf(v0, bf2f_hi(x0.y), a3);
        a0 = fmaf(v1, bf2f_lo(x1.x), a0); a1 = fmaf(v1, bf2f_hi(x1.x), a1);
        a2 = fmaf(v1, bf2f_lo(x1.y), a2); a3 = fmaf(v1, bf2f_hi(x1.y), a3);
        a0 = fmaf(v2, bf2f_lo(x2.x), a0); a1 = fmaf(v2, bf2f_hi(x2.x), a1);
        a2 = fmaf(v2, bf2f_lo(x2.y), a2); a3 = fmaf(v2, bf2f_hi(x2.y), a3);
        a0 = fmaf(v3, bf2f_lo(x3.x), a0); a1 = fmaf(v3, bf2f_hi(x3.x), a1);
        a2 = fmaf(v3, bf2f_lo(x3.y), a2); a3 = fmaf(v3, bf2f_hi(x3.y), a3);
        a0 = fmaf(v4, bf2f_lo(x4_.x), a0); a1 = fmaf(v4, bf2f_hi(x4_.x), a1);
        a2 = fmaf(v4, bf2f_lo(x4_.y), a2); a3 = fmaf(v4, bf2f_hi(x4_.y), a3);
        a0 = fmaf(v5, bf2f_lo(x5.x), a0); a1 = fmaf(v5, bf2f_hi(x5.x), a1);
        a2 = fmaf(v5, bf2f_lo(x5.y), a2); a3 = fmaf(v5, bf2f_hi(x5.y), a3);
        a0 = fmaf(v6, bf2f_lo(x6.x), a0); a1 = fmaf(v6, bf2f_hi(x6.x), a1);
        a2 = fmaf(v6, bf2f_lo(x6.y), a2); a3 = fmaf(v6, bf2f_hi(x6.y), a3);
        a0 = fmaf(v7, bf2f_lo(x7.x), a0); a1 = fmaf(v7, bf2f_hi(x7.x), a1);
        a2 = fmaf(v7, bf2f_lo(x7.y), a2); a3 = fmaf(v7, bf2f_hi(x7.y), a3);
    }
    for (; i + 2 <= e; i += 2) {
        int4 pa = *reinterpret_cast<const int4*>(pr + i);
        uint2 x0 = xb[(size_t)pa.x * 64 + lane];
        uint2 x1 = xb[(size_t)pa.z * 64 + lane];
        float v0 = __int_as_float(pa.y), v1 = __int_as_float(pa.w);
        a0 = fmaf(v0, bf2f_lo(x0.x), a0); a1 = fmaf(v0, bf2f_hi(x0.x), a1);
        a2 = fmaf(v0, bf2f_lo(x0.y), a2); a3 = fmaf(v0, bf2f_hi(x0.y), a3);
        a0 = fmaf(v1, bf2f_lo(x1.x), a0); a1 = fmaf(v1, bf2f_hi(x1.x), a1);
        a2 = fmaf(v1, bf2f_lo(x1.y), a2); a3 = fmaf(v1, bf2f_hi(x1.y), a3);
    }
    for (; i < e; ++i) {
        int2 p = pr[i];
        uint2 xv = xb[(size_t)p.x * 64 + lane];
        float v = __int_as_float(p.y);
        a0 = fmaf(v, bf2f_lo(xv.x), a0);
        a1 = fmaf(v, bf2f_hi(xv.x), a1);
        a2 = fmaf(v, bf2f_lo(xv.y), a2);
        a3 = fmaf(v, bf2f_hi(xv.y), a3);
    }
    out4[(size_t)wid * 64 + lane] = make_float4(a0, a1, a2, a3);
}

// f32 fallback (small ws)
__global__ void spmm_f32_kernel(const float4* __restrict__ x4, const int* __restrict__ offs,
                                const int2* __restrict__ pr, float4* __restrict__ out4,
                                int nnodes) {
    int wid = (blockIdx.x * blockDim.x + threadIdx.x) >> 6;
    int lane = threadIdx.x & 63;
    if (wid >= nnodes) return;
    int s = offs[wid], e = offs[wid + 1];
    float4 acc = make_float4(0.f, 0.f, 0.f, 0.f);
    for (int i = s; i < e; ++i) {
        int2 p = pr[i];
        float4 xv = x4[(size_t)p.x * 64 + lane];
        float v = __int_as_float(p.y);
        acc.x = fmaf(v, xv.x, acc.x); acc.y = fmaf(v, xv.y, acc.y);
        acc.z = fmaf(v, xv.z, acc.z); acc.w = fmaf(v, xv.w, acc.w);
    }
    out4[(size_t)wid * 64 + lane] = acc;
}

// ---------------- In-place MFMA GEMM: out = agg @ W^T + b ----------------
__launch_bounds__(256, 2)
__global__ void gemm_mfma_kernel(float* __restrict__ out, const unsigned short* __restrict__ Wb,
                                 const float* __restrict__ bias, int nrows) {
    __shared__ unsigned short As[64][264];  // 256 + 8 pad
    __shared__ unsigned short Ws[256][40];  // 32 + 8 pad (one k-slice)
    int tid = threadIdx.x;
    int rowBase = blockIdx.x * 64;

    const float4* o4 = reinterpret_cast<const float4*>(out);
    for (int it = tid; it < 64 * 64; it += 256) {
        int r = it >> 6, c = it & 63;
        float4 v = make_float4(0.f, 0.f, 0.f, 0.f);
        int gr = rowBase + r;
        if (gr < nrows) v = o4[(size_t)gr * 64 + c];
        ushort4 w;
        w.x = f2bf(v.x); w.y = f2bf(v.y); w.z = f2bf(v.z); w.w = f2bf(v.w);
        *reinterpret_cast<ushort4*>(&As[r][c * 4]) = w;
    }

    int w = tid >> 6, lane = tid & 63;
    int lr = lane & 15, lg = lane >> 4;
    f32x4 acc[16];
    #pragma unroll
    for (int nt = 0; nt < 16; ++nt) acc[nt] = (f32x4){0.f, 0.f, 0.f, 0.f};

    for (int k0 = 0; k0 < 256; k0 += 32) {
        __syncthreads();
        for (int it = tid; it < 1024; it += 256) {
            int r = it >> 2, c = it & 3;
            uint4 v = *reinterpret_cast<const uint4*>(Wb + (size_t)r * 256 + k0 + c * 8);
            *reinterpret_cast<uint4*>(&Ws[r][c * 8]) = v;
        }
        __syncthreads();
        short8 af = *reinterpret_cast<const short8*>(&As[w * 16 + lr][k0 + 8 * lg]);
        #pragma unroll
        for (int nt = 0; nt < 16; ++nt) {
            short8 bf_ = *reinterpret_cast<const short8*>(&Ws[nt * 16 + lr][8 * lg]);
            acc[nt] = __builtin_amdgcn_mfma_f32_16x16x32_bf16(af, bf_, acc[nt], 0, 0, 0);
        }
    }

    #pragma unroll
    for (int nt = 0; nt < 16; ++nt) {
        int gc = nt * 16 + lr;
        float bv = bias[gc];
        #pragma unroll
        for (int q = 0; q < 4; ++q) {
            int gr = rowBase + w * 16 + lg * 4 + q;
            if (gr < nrows) out[(size_t)gr * 256 + gc] = acc[nt][q] + bv;
        }
    }
}

// ---------------- launch ----------------

extern "C" void kernel_launch(void* const* d_in, const int* in_sizes, int n_in,
                              void* d_out, int out_size, void* d_ws, size_t ws_size,
                              hipStream_t stream) {
    const float* x     = (const float*)d_in[0];
    const int*   erow  = (const int*)d_in[1];
    const int*   ecol  = (const int*)d_in[2];
    const float* evalv = (const float*)d_in[3];
    const float* W     = (const float*)d_in[4];
    const float* bias  = (const float*)d_in[5];
    float* out = (float*)d_out;

    int n_nodes = in_sizes[0] / 256;
    int n_edges = in_sizes[1];
    int nb = (n_nodes + 1023) >> 10;  // scan blocks

    // workspace layout (int units): cnt | offs | cur | bsum | Wb | pr | xb
    size_t A = (size_t)((n_nodes + 63) & ~63);
    int* cnt   = (int*)d_ws;
    int* offs  = cnt + A;                 // n_nodes+1 <= A (A is rounded up)
    int* cur   = offs + A;
    int* bsum  = cur + A;                 // nb+1 ints
    int* wbase = bsum + (((size_t)nb + 64) & ~63ull);
    unsigned short* Wb = (unsigned short*)wbase;            // 256*256 bf16
    int2* pr   = (int2*)(wbase + 32768);                    // n_edges int2
    unsigned short* xb = (unsigned short*)(pr + n_edges);   // n_nodes*256 bf16
    size_t need_bf16 = (size_t)((char*)(xb + (size_t)n_nodes * 256) - (char*)d_ws);
    bool use_bf16 = ws_size >= need_bf16;

    zero_kernel<<<(n_nodes + THREADS - 1) / THREADS, THREADS, 0, stream>>>(cnt, n_nodes);
    hist_part_kernel<<<2048, THREADS, 0, stream>>>(erow, cnt, n_edges, n_nodes);
    scan1_kernel<<<nb, THREADS, 0, stream>>>(cnt, offs, bsum, n_nodes);
    scan2_kernel<<<1, THREADS, 0, stream>>>(bsum, nb);
    scan3_kernel<<<(n_nodes + THREADS - 1) / THREADS, THREADS, 0, stream>>>(offs, bsum, cur, n_nodes);
    place_part_kernel<<<2048, THREADS, 0, stream>>>(erow, ecol, evalv, cur, pr, n_edges, n_nodes);

    cvt_bf16_kernel<<<32, THREADS, 0, stream>>>((const float4*)W, (uint4*)Wb, 65536 / 8);

    int spmm_blocks = (n_nodes + 3) / 4;  // 4 waves/block, 1 wave/node
    if (use_bf16) {
        int n8 = n_nodes * 32;
        cvt_bf16_kernel<<<(n8 + THREADS - 1) / THREADS, THREADS, 0, stream>>>(
            (const float4*)x, (uint4*)xb, n8);
        spmm_bf16_kernel<<<spmm_blocks, THREADS, 0, stream>>>(
            (const uint2*)xb, offs, pr, (float4*)out, n_nodes);
    } else {
        spmm_f32_kernel<<<spmm_blocks, THREADS, 0, stream>>>(
            (const float4*)x, offs, pr, (float4*)out, n_nodes);
    }

    int gemm_blocks = (n_nodes + 63) / 64;
    gemm_mfma_kernel<<<gemm_blocks, THREADS, 0, stream>>>(out, Wb, bias, n_nodes);
}